// Round 1
// baseline (139.443 us; speedup 1.0000x reference)
//
#include <hip/hip_runtime.h>
#include <hip/hip_bf16.h>

// Chamfer loss, B=16, N=4096, D=3, fp32.
// out[0 .. B*N)    = min over src i of ||x_i - y_j||^2   (per trg point j)
// out[B*N .. 2B*N) = min over trg j of ||x_i - y_j||^2   (per src point i)

#define CH_B 16
#define CH_N 4096
#define CH_BLOCK 256
#define CH_RPT 4                       // output points per thread (registers)
#define CH_JT (CH_BLOCK * CH_RPT)      // 1024 output points per block
#define CH_NJB (CH_N / CH_JT)          // 4 output tiles per batch
#define CH_SPLIT 4                     // i-slices per output tile
#define CH_ISZ (CH_N / CH_SPLIT)       // 1024 looped points per block

__global__ __launch_bounds__(CH_BLOCK) void chamfer_init(unsigned int* out, int n) {
    int idx = blockIdx.x * CH_BLOCK + threadIdx.x;
    if (idx < n) out[idx] = 0x7f800000u;  // +inf
}

// P: looped-over set [B,N,3]; Q: per-thread-owned set [B,N,3]
// out[b*N + q] = min over this block's P-slice of dist2(P[p], Q[q]), combined by atomicMin on bits.
__global__ __launch_bounds__(CH_BLOCK) void chamfer_dir(
    const float* __restrict__ P,
    const float* __restrict__ Q,
    unsigned int* __restrict__ out)
{
    __shared__ float sp[CH_ISZ * 3];  // 12 KB

    const int b   = blockIdx.z;
    const int jb  = blockIdx.x;   // which output tile
    const int isl = blockIdx.y;   // which i-slice

    const float* Pb = P + (size_t)b * CH_N * 3 + (size_t)isl * CH_ISZ * 3;
    const float* Qb = Q + (size_t)b * CH_N * 3;

    // Stage P slice into LDS: 3072 floats = 768 float4, 3 per thread, coalesced.
    {
        const float4* s4 = (const float4*)Pb;
        float4*       d4 = (float4*)sp;
        #pragma unroll
        for (int t = 0; t < (CH_ISZ * 3 / 4) / CH_BLOCK; ++t)
            d4[t * CH_BLOCK + threadIdx.x] = s4[t * CH_BLOCK + threadIdx.x];
    }
    __syncthreads();

    // Load my Q points (stride CH_BLOCK between the RPT points).
    const int j0 = jb * CH_JT + threadIdx.x;
    float qx[CH_RPT], qy[CH_RPT], qz[CH_RPT], m[CH_RPT];
    #pragma unroll
    for (int r = 0; r < CH_RPT; ++r) {
        const int j = j0 + r * CH_BLOCK;
        qx[r] = Qb[j * 3 + 0];
        qy[r] = Qb[j * 3 + 1];
        qz[r] = Qb[j * 3 + 2];
        m[r]  = __builtin_inff();
    }

    // Main loop: broadcast LDS reads (uniform address -> no bank conflicts),
    // 3 ds_read + RPT*7 VALU per i.
    #pragma unroll 4
    for (int i = 0; i < CH_ISZ; ++i) {
        const float px = sp[i * 3 + 0];
        const float py = sp[i * 3 + 1];
        const float pz = sp[i * 3 + 2];
        #pragma unroll
        for (int r = 0; r < CH_RPT; ++r) {
            const float dx = qx[r] - px;
            const float dy = qy[r] - py;
            const float dz = qz[r] - pz;
            const float d  = dx * dx + dy * dy + dz * dz;
            m[r] = fminf(m[r], d);
        }
    }

    #pragma unroll
    for (int r = 0; r < CH_RPT; ++r) {
        const int j = j0 + r * CH_BLOCK;
        atomicMin(&out[(size_t)b * CH_N + j], __float_as_uint(m[r]));
    }
}

extern "C" void kernel_launch(void* const* d_in, const int* in_sizes, int n_in,
                              void* d_out, int out_size, void* d_ws, size_t ws_size,
                              hipStream_t stream) {
    const float* src = (const float*)d_in[0];
    const float* trg = (const float*)d_in[1];
    unsigned int* out = (unsigned int*)d_out;

    const int total = CH_B * CH_N;  // 65536 per output

    // Init both outputs to +inf.
    chamfer_init<<<dim3((2 * total + CH_BLOCK - 1) / CH_BLOCK), dim3(CH_BLOCK), 0, stream>>>(out, 2 * total);

    dim3 grid(CH_NJB, CH_SPLIT, CH_B);
    dim3 block(CH_BLOCK);

    // Output 0: min over src (i) for each trg point j -> loop P=src, own Q=trg.
    chamfer_dir<<<grid, block, 0, stream>>>(src, trg, out);
    // Output 1: min over trg (j) for each src point i -> loop P=trg, own Q=src.
    chamfer_dir<<<grid, block, 0, stream>>>(trg, src, out + total);
}

// Round 2
// 48.047 us; speedup vs baseline: 2.9022x; 2.9022x over previous
//
#include <hip/hip_runtime.h>
#include <hip/hip_bf16.h>

// Chamfer loss, B=16, N=4096, D=3, fp32.
// out[0 .. B*N)    = min over src i of ||x_i - y_j||^2   (per trg point j)
// out[B*N .. 2B*N) = min over trg j of ||x_i - y_j||^2   (per src point i)
//
// dist2 = ||p||^2 + ||q||^2 - 2 p.q  (same expansion as the reference).
// LDS holds (-2px, -2py, -2pz, ||p||^2) per looped point -> 4 VALU/pair:
//   acc = fma(-2px, qx, pn); acc = fma(-2py, qy, acc); acc = fma(-2pz, qz, acc);
//   m = min(m, acc);   ... final out = max(m + ||q||^2, 0)

#define CH_B 16
#define CH_N 4096
#define CH_BLOCK 256
#define CH_RPT 4                       // output points per thread
#define CH_JT (CH_BLOCK * CH_RPT)      // 1024 output points per block
#define CH_NJB (CH_N / CH_JT)          // 4 output tiles per batch
#define CH_SPLIT 16                    // i-slices per output tile
#define CH_ISZ (CH_N / CH_SPLIT)       // 256 looped points per block (== CH_BLOCK)

__global__ __launch_bounds__(CH_BLOCK) void chamfer_dir(
    const float* __restrict__ src,
    const float* __restrict__ trg,
    unsigned int* __restrict__ out_all)
{
    __shared__ float4 sp[CH_ISZ];  // 4 KB: (-2px, -2py, -2pz, pn)

    const int bz  = blockIdx.z;       // 0..31: batch + direction
    const int b   = bz & (CH_B - 1);
    const int dir = bz >> 4;          // 0: loop src / own trg; 1: loop trg / own src

    const float* P = dir ? trg : src;
    const float* Q = dir ? src : trg;
    unsigned int* out = out_all + (size_t)dir * CH_B * CH_N + (size_t)b * CH_N;

    const int jb  = blockIdx.x;   // output tile
    const int isl = blockIdx.y;   // i-slice

    const float* Pb = P + ((size_t)b * CH_N + (size_t)isl * CH_ISZ) * 3;
    const float* Qb = Q + (size_t)b * CH_N * 3;

    // Stage: one looped point per thread (CH_ISZ == CH_BLOCK).
    {
        const int t = threadIdx.x;
        const float px = Pb[t * 3 + 0];
        const float py = Pb[t * 3 + 1];
        const float pz = Pb[t * 3 + 2];
        sp[t] = make_float4(-2.0f * px, -2.0f * py, -2.0f * pz,
                            px * px + py * py + pz * pz);
    }
    __syncthreads();

    // My output points.
    const int j0 = jb * CH_JT + threadIdx.x;
    float qx[CH_RPT], qy[CH_RPT], qz[CH_RPT], qn[CH_RPT], m[CH_RPT];
    #pragma unroll
    for (int r = 0; r < CH_RPT; ++r) {
        const int j = j0 + r * CH_BLOCK;
        qx[r] = Qb[j * 3 + 0];
        qy[r] = Qb[j * 3 + 1];
        qz[r] = Qb[j * 3 + 2];
        qn[r] = qx[r] * qx[r] + qy[r] * qy[r] + qz[r] * qz[r];
        m[r]  = __builtin_inff();
    }

    // Main loop: 1 broadcast ds_read_b128 + CH_RPT*4 VALU per i.
    #pragma unroll 4
    for (int i = 0; i < CH_ISZ; ++i) {
        const float4 p = sp[i];
        #pragma unroll
        for (int r = 0; r < CH_RPT; ++r) {
            float acc = __builtin_fmaf(p.x, qx[r], p.w);
            acc       = __builtin_fmaf(p.y, qy[r], acc);
            acc       = __builtin_fmaf(p.z, qz[r], acc);
            m[r]      = fminf(m[r], acc);
        }
    }

    #pragma unroll
    for (int r = 0; r < CH_RPT; ++r) {
        const int j = j0 + r * CH_BLOCK;
        const float v = fmaxf(m[r] + qn[r], 0.0f);  // >=0 so uint-bit min order is valid
        atomicMin(&out[j], __float_as_uint(v));
    }
}

extern "C" void kernel_launch(void* const* d_in, const int* in_sizes, int n_in,
                              void* d_out, int out_size, void* d_ws, size_t ws_size,
                              hipStream_t stream) {
    const float* src = (const float*)d_in[0];
    const float* trg = (const float*)d_in[1];
    unsigned int* out = (unsigned int*)d_out;

    // Init both outputs to 0x7f7f7f7f (~3.4e38 as float): valid "+infinity"
    // under uint-ordered min for nonnegative distances.
    hipMemsetAsync(out, 0x7f, (size_t)2 * CH_B * CH_N * sizeof(float), stream);

    dim3 grid(CH_NJB, CH_SPLIT, 2 * CH_B);
    dim3 block(CH_BLOCK);
    chamfer_dir<<<grid, block, 0, stream>>>(src, trg, out);
}